// Round 4
// baseline (56.378 us; speedup 1.0000x reference)
//
#include <hip/hip_runtime.h>
#include <hip/hip_bf16.h>
#include <math.h>

#define SRATE   44100
#define HOPSZ   512
#define NFFT    2048
#define PADW    1024
#define NBINS   540
#define NFRAMES 431
#define NSAMP   220500
#define NBATCH  16

#define PI_D 3.14159265358979323846

typedef __attribute__((ext_vector_type(8))) short short8;
typedef __attribute__((ext_vector_type(4))) float f32x4;

// ======================= PATH A: flattened-M pipelined GEMM =================
// M = batch*frames = 6896 rows. Tile 128(M) x 64(N cols = 32 bins), BK=64.
// 17 active N-tiles (bins 0..543, last 4 dummy); tile 18 (all dummy) skipped.
#define MROWS   (NBATCH * NFRAMES)      // 6896
#define BM2     128
#define BN2     64
#define BK2     64
#define MT2     54                      // ceil(6896/128)
#define NT2     17
#define TABCOLS 1088                    // 17*64 cols built
#define XPITCH  222552                  // bf16 elems per batch (NSAMP+2048 -> mult 8)
#define XPTOT   (NBATCH * XPITCH)       // 3,560,832 elems
#define NCHUNK  (XPITCH / 8)            // 27819
#define CVTBLK  ((NBATCH * NCHUNK + 255) / 256)   // 1739

// ---- fused prep: x->bf16 xp (blocks < CVTBLK) + swizzled atom table --------
__global__ void prep_all(const float* __restrict__ x,
                         __hip_bfloat16* __restrict__ xp,
                         __hip_bfloat16* __restrict__ tab) {
    const int bid = blockIdx.x;
    if (bid < CVTBLK) {
        const int idx = bid * 256 + threadIdx.x;
        if (idx >= NBATCH * NCHUNK) return;
        const int b  = idx / NCHUNK;
        const int c  = idx - b * NCHUNK;
        const int i0 = c * 8;
        const float* xb = x + (size_t)b * NSAMP;
        const int g0 = i0 - PADW;
        union { short8 v; unsigned short u[8]; } pk;
        if (g0 >= 0 && g0 + 8 <= NSAMP) {
            const float4 f0 = *(const float4*)(xb + g0);
            const float4 f1 = *(const float4*)(xb + g0 + 4);
            const float vv[8] = {f0.x, f0.y, f0.z, f0.w, f1.x, f1.y, f1.z, f1.w};
            #pragma unroll
            for (int e = 0; e < 8; ++e) {
                __hip_bfloat16 h = __float2bfloat16(vv[e]);
                pk.u[e] = *(unsigned short*)&h;
            }
        } else {
            #pragma unroll
            for (int e = 0; e < 8; ++e) {
                const int g = g0 + e;
                const float v = (g >= 0 && g < NSAMP) ? xb[g] : 0.f;
                __hip_bfloat16 h = __float2bfloat16(v);
                pk.u[e] = *(unsigned short*)&h;
            }
        }
        *(short8*)(xp + (size_t)b * XPITCH + i0) = pk.v;
        return;
    }
    // ---- atom table col, PRE-SWIZZLED: value(k) at chunk (k/8)^(col&7) -----
    const int col = bid - CVTBLK;                     // 0..1087
    const int bin = col >> 1;
    const int ri  = col & 1;
    __hip_bfloat16* row = tab + (size_t)col * NFFT;
    if (bin >= NBINS) {
        const __hip_bfloat16 z = __float2bfloat16(0.f);
        for (int t = threadIdx.x; t < NFFT; t += blockDim.x) row[t] = z;
        return;
    }
    const double freq  = 27.5 * exp2((double)bin / 60.0);
    const double r     = exp2(2.0 / 60.0);
    const double alpha = (r - 1.0) / (r + 1.0);
    const double len   = (1.0 / alpha) * (double)SRATE / (freq + 30.0 / alpha);
    const int    nk    = (int)floor(len);
    const int    s     = (NFFT - nk) / 2;
    const float  ampf  = (float)((2.0 / (double)(nk - 1)) / sqrt(len));
    const float  winc  = 2.0f / (float)(nk - 1);
    const double phs   = 2.0 * freq / (double)SRATE;  // revolutions per tap
    const int xr = col & 7;
    for (int t = threadIdx.x; t < NFFT; t += blockDim.x) {
        float val = 0.f;
        const int tp = t - s;
        if (tp >= 0 && tp < nk) {
            const float w = 0.5f - 0.5f * cospif(winc * (float)tp);
            const double ph = fmod(phs * (double)tp, 2.0);
            float sp, cp;
            sincospif((float)ph, &sp, &cp);
            val = ri ? (-w * ampf * sp) : (w * ampf * cp);
        }
        const int kpos = ((((t >> 3) ^ xr) & 0xff) << 3) | (t & 7);
        row[kpos] = __float2bfloat16(val);
    }
}

// ---- GEMM: out[row*540+bin] = |sum_k xp_row[k] * atom_col[k]| --------------
__device__ __forceinline__ short8 lds_frag(const char* base, int row, int ko) {
    const int off = (row << 7) + (((ko >> 3) ^ (row & 7)) << 4);
    return *(const short8*)(base + off);
}

__global__ __launch_bounds__(256, 3) void vqt_gemm3(const __hip_bfloat16* __restrict__ xp,
                                                    const __hip_bfloat16* __restrict__ tab,
                                                    float* __restrict__ out) {
    // 48 KB: [buf][A 16K | B 8K] -> 3 blocks/CU
    __shared__ uint4 smem4[3072];
    const int mt = blockIdx.x, nt = blockIdx.y;
    const int row0 = mt * BM2;
    const int n0   = nt * BN2;

    // K clip from lowest (longest-support) bin of tile (supports nested)
    const int    bin0  = n0 >> 1;
    const double freq  = 27.5 * exp2((double)bin0 / 60.0);
    const double rr    = exp2(2.0 / 60.0);
    const double alpha = (rr - 1.0) / (rr + 1.0);
    const double len   = (1.0 / alpha) * (double)SRATE / (freq + 30.0 / alpha);
    const int    nk    = (int)floor(len);
    const int    s     = (NFFT - nk) / 2;
    const int    k0    = s & ~(BK2 - 1);
    int          k1    = (s + nk + BK2 - 1) & ~(BK2 - 1);
    if (k1 > NFFT) k1 = NFFT;
    const int nsteps = (k1 - k0) >> 6;

    const int t    = threadIdx.x;
    const int lane = t & 63;
    const int w    = t >> 6;
    const int wr   = w >> 1, wc = w & 1;              // wave -> 64x32 sub-tile
    const int l15  = lane & 15, kq = lane >> 4;

    // staging sources: thread t stages 16B chunk c = t + 256p
    const __hip_bfloat16* srcA[4];
    const __hip_bfloat16* srcB[2];
    #pragma unroll
    for (int p = 0; p < 4; ++p) {
        const int c  = t + 256 * p;
        const int lr = c >> 3;                        // A row 0..127
        const int kc = c & 7;
        int row = row0 + lr;
        if (row > MROWS - 1) row = MROWS - 1;
        const int bb = row / NFRAMES;
        const int ff = row - bb * NFRAMES;
        srcA[p] = xp + (size_t)bb * XPITCH + (size_t)ff * HOPSZ
                     + ((kc ^ (lr & 7)) << 3) + k0;
    }
    #pragma unroll
    for (int p = 0; p < 2; ++p) {
        const int c  = t + 256 * p;
        const int lr = c >> 3;                        // B row 0..63
        const int kc = c & 7;
        srcB[p] = tab + (size_t)(n0 + lr) * NFFT + (kc << 3) + k0;  // pre-swizzled
    }

    f32x4 acc[4][2] = {};

    #define STAGE(BUF)                                                            \
        do {                                                                      \
            const int cb = (BUF) * 1536;                                          \
            _Pragma("unroll")                                                     \
            for (int p = 0; p < 4; ++p) {                                         \
                __builtin_amdgcn_global_load_lds((const void*)srcA[p],            \
                    (void*)&smem4[cb + p * 256 + w * 64], 16, 0, 0);              \
                srcA[p] += BK2;                                                   \
            }                                                                     \
            _Pragma("unroll")                                                     \
            for (int p = 0; p < 2; ++p) {                                         \
                __builtin_amdgcn_global_load_lds((const void*)srcB[p],            \
                    (void*)&smem4[cb + 1024 + p * 256 + w * 64], 16, 0, 0);       \
                srcB[p] += BK2;                                                   \
            }                                                                     \
        } while (0)

    STAGE(0);
    __syncthreads();

    int buf = 0;
    for (int step = 0; step < nsteps; ++step) {
        if (step + 1 < nsteps) STAGE(buf ^ 1);
        const char* Ab = (const char*)smem4 + buf * 24576;
        const char* Bb = Ab + 16384;
        #pragma unroll
        for (int ks = 0; ks < 2; ++ks) {
            const int ko = ks * 32 + kq * 8;
            short8 af[4], bf[2];
            #pragma unroll
            for (int i = 0; i < 4; ++i) af[i] = lds_frag(Ab, wr * 64 + i * 16 + l15, ko);
            #pragma unroll
            for (int j = 0; j < 2; ++j) bf[j] = lds_frag(Bb, wc * 32 + j * 16 + l15, ko);
            #pragma unroll
            for (int i = 0; i < 4; ++i)
                #pragma unroll
                for (int j = 0; j < 2; ++j)
                    acc[i][j] = __builtin_amdgcn_mfma_f32_16x16x32_bf16(af[i], bf[j], acc[i][j], 0, 0, 0);
        }
        __syncthreads();
        buf ^= 1;
    }
    #undef STAGE

    // ---- epilogue: |(re,im)| of adjacent-lane pairs, compacted to 16 bins
    const int rowb = row0 + wr * 64;
    const int binb = (n0 + wc * 32) >> 1;
    const int srcl = (lane & 48) | ((l15 & 7) << 1);
    #pragma unroll
    for (int i = 0; i < 4; ++i) {
        #pragma unroll
        for (int reg = 0; reg < 4; ++reg) {
            const float v0 = acc[i][0][reg];
            const float v1 = acc[i][1][reg];
            const float p0 = __shfl_xor(v0, 1);
            const float p1 = __shfl_xor(v1, 1);
            const float m0 = sqrtf(v0 * v0 + p0 * p0);
            const float m1 = sqrtf(v1 * v1 + p1 * p1);
            const float r0 = __shfl(m0, srcl);
            const float r1 = __shfl(m1, srcl);
            const float m  = (l15 < 8) ? r0 : r1;
            const int row = rowb + i * 16 + kq * 4 + reg;
            const int bin = binb + l15;
            if (row < MROWS && bin < NBINS)
                out[(size_t)row * NBINS + bin] = m;
        }
    }
}

// ======================= PATH B fallback: round-2 kernel ====================
#define NPADB   544
#define NCOLS   1088
#define BM 64
#define BN 64
#define BK 64
#define MTILES 7
#define NTILES 17
#define APITCH 72

__global__ void build_tab(__hip_bfloat16* __restrict__ tab) {
    const int bin = blockIdx.x;
    __hip_bfloat16* rowre = tab + (size_t)(2 * bin) * NFFT;
    __hip_bfloat16* rowim = rowre + NFFT;
    if (bin >= NBINS) {
        const __hip_bfloat16 z = __float2bfloat16(0.f);
        for (int t = threadIdx.x; t < NFFT; t += blockDim.x) { rowre[t] = z; rowim[t] = z; }
        return;
    }
    const double freq  = 27.5 * exp2((double)bin / 60.0);
    const double r     = exp2(2.0 / 60.0);
    const double alpha = (r - 1.0) / (r + 1.0);
    const double len   = (1.0 / alpha) * (double)SRATE / (freq + 30.0 / alpha);
    const int    nk    = (int)floor(len);
    const int    s     = (NFFT - nk) / 2;
    const double amp   = (2.0 / (double)(nk - 1)) / sqrt(len);
    for (int t = threadIdx.x; t < NFFT; t += blockDim.x) {
        float re = 0.f, im = 0.f;
        const int tp = t - s;
        if (tp >= 0 && tp < nk) {
            const double w  = 0.5 - 0.5 * cos(2.0 * PI_D * (double)tp / (double)(nk - 1));
            const double ph = fmod(2.0 * freq * (double)tp / (double)SRATE, 2.0);
            double sp, cp;
            sincospi(ph, &sp, &cp);
            re = (float)(w * amp * cp);
            im = (float)(-w * amp * sp);
        }
        rowre[t] = __float2bfloat16(re);
        rowim[t] = __float2bfloat16(im);
    }
}

__global__ __launch_bounds__(256) void vqt_gemm(const float* __restrict__ x,
                                                const __hip_bfloat16* __restrict__ tab,
                                                float* __restrict__ out) {
    __shared__ __hip_bfloat16 As[BM * APITCH];
    __shared__ __hip_bfloat16 Bs[BN * APITCH];
    const int mt = blockIdx.x, nt = blockIdx.y, b = blockIdx.z;
    const int n0 = nt * BN;
    const int    bin0  = n0 >> 1;
    const double freq  = 27.5 * exp2((double)bin0 / 60.0);
    const double r     = exp2(2.0 / 60.0);
    const double alpha = (r - 1.0) / (r + 1.0);
    const double len   = (1.0 / alpha) * (double)SRATE / (freq + 30.0 / alpha);
    const int    nk    = (int)floor(len);
    const int    s     = (NFFT - nk) / 2;
    const int    k0    = s & ~(BK - 1);
    int          k1    = (s + nk + BK - 1) & ~(BK - 1);
    if (k1 > NFFT) k1 = NFFT;
    const int tid  = threadIdx.x;
    const int lane = tid & 63;
    const int wid  = tid >> 6;
    const int wr   = wid >> 1, wc = wid & 1;
    const int sr   = tid >> 2, sq = tid & 3;
    const float* xb     = x + (size_t)b * NSAMP;
    const int    f_base = mt * BM;
    const long arow_off = (long)(f_base + sr) * HOPSZ - PADW + sq * 16;
    const __hip_bfloat16* brow = tab + (size_t)(n0 + sr) * NFFT + sq * 16;
    f32x4 acc[2][2] = {};
    for (int kt = k0; kt < k1; kt += BK) {
        union { short8 v[2]; unsigned short u[16]; } pk;
        #pragma unroll
        for (int v = 0; v < 4; ++v) {
            const long g = arow_off + kt + v * 4;
            float4 t4 = {0.f, 0.f, 0.f, 0.f};
            if (g >= 0 && g + 4 <= (long)NSAMP) t4 = *(const float4*)(xb + g);
            __hip_bfloat16 h0 = __float2bfloat16(t4.x);
            __hip_bfloat16 h1 = __float2bfloat16(t4.y);
            __hip_bfloat16 h2 = __float2bfloat16(t4.z);
            __hip_bfloat16 h3 = __float2bfloat16(t4.w);
            pk.u[4 * v + 0] = *(unsigned short*)&h0;
            pk.u[4 * v + 1] = *(unsigned short*)&h1;
            pk.u[4 * v + 2] = *(unsigned short*)&h2;
            pk.u[4 * v + 3] = *(unsigned short*)&h3;
        }
        { short8* dst = (short8*)(As + sr * APITCH + sq * 16); dst[0] = pk.v[0]; dst[1] = pk.v[1]; }
        { const short8* src = (const short8*)(brow + kt);
          short8* dst = (short8*)(Bs + sr * APITCH + sq * 16); dst[0] = src[0]; dst[1] = src[1]; }
        __syncthreads();
        #pragma unroll
        for (int ks = 0; ks < 2; ++ks) {
            const int kc = ks * 32 + (lane >> 4) * 8;
            const short8 a0 = *(const short8*)(As + (wr * 32 +      (lane & 15)) * APITCH + kc);
            const short8 a1 = *(const short8*)(As + (wr * 32 + 16 + (lane & 15)) * APITCH + kc);
            const short8 b0 = *(const short8*)(Bs + (wc * 32 +      (lane & 15)) * APITCH + kc);
            const short8 b1 = *(const short8*)(Bs + (wc * 32 + 16 + (lane & 15)) * APITCH + kc);
            acc[0][0] = __builtin_amdgcn_mfma_f32_16x16x32_bf16(a0, b0, acc[0][0], 0, 0, 0);
            acc[0][1] = __builtin_amdgcn_mfma_f32_16x16x32_bf16(a0, b1, acc[0][1], 0, 0, 0);
            acc[1][0] = __builtin_amdgcn_mfma_f32_16x16x32_bf16(a1, b0, acc[1][0], 0, 0, 0);
            acc[1][1] = __builtin_amdgcn_mfma_f32_16x16x32_bf16(a1, b1, acc[1][1], 0, 0, 0);
        }
        __syncthreads();
    }
    const int colc = lane & 15, rg = lane >> 4;
    float* outb = out + (size_t)b * NFRAMES * NBINS;
    #pragma unroll
    for (int i = 0; i < 2; ++i)
        #pragma unroll
        for (int j = 0; j < 2; ++j)
            #pragma unroll
            for (int reg = 0; reg < 4; ++reg) {
                const float v = acc[i][j][reg];
                const float p = __shfl_xor(v, 1);
                if (!(lane & 1)) {
                    const int f   = f_base + wr * 32 + i * 16 + rg * 4 + reg;
                    const int col = n0 + wc * 32 + j * 16 + colc;
                    const int bin = col >> 1;
                    if (f < NFRAMES && bin < NBINS)
                        outb[(size_t)f * NBINS + bin] = sqrtf(v * v + p * p);
                }
            }
}

extern "C" void kernel_launch(void* const* d_in, const int* in_sizes, int n_in,
                              void* d_out, int out_size, void* d_ws, size_t ws_size,
                              hipStream_t stream) {
    const float* x = (const float*)d_in[0];
    float* out = (float*)d_out;
    const size_t needA = (size_t)(XPTOT + (size_t)TABCOLS * NFFT) * 2;  // 11.58 MB
    const size_t needB = (size_t)NCOLS * NFFT * sizeof(__hip_bfloat16); // 4.46 MB
    if (ws_size >= needA) {
        __hip_bfloat16* xp  = (__hip_bfloat16*)d_ws;
        __hip_bfloat16* tab = xp + XPTOT;
        prep_all<<<dim3(CVTBLK + TABCOLS), dim3(256), 0, stream>>>(x, xp, tab);
        vqt_gemm3<<<dim3(MT2, NT2), dim3(256), 0, stream>>>(xp, tab, out);
    } else if (ws_size >= needB) {
        build_tab<<<dim3(NPADB), dim3(256), 0, stream>>>((__hip_bfloat16*)d_ws);
        vqt_gemm<<<dim3(MTILES, NTILES, NBATCH), dim3(256), 0, stream>>>(
            x, (const __hip_bfloat16*)d_ws, out);
    }
}

// Round 5
// 56.331 us; speedup vs baseline: 1.0008x; 1.0008x over previous
//
#include <hip/hip_runtime.h>
#include <hip/hip_bf16.h>
#include <math.h>

#define SRATE   44100
#define HOPSZ   512
#define NFFT    2048
#define PADW    1024
#define NBINS   540
#define NFRAMES 431
#define NSAMP   220500
#define NBATCH  16

#define PI_D 3.14159265358979323846

typedef __attribute__((ext_vector_type(8))) short short8;
typedef __attribute__((ext_vector_type(4))) float f32x4;

// ======================= PATH A: flattened-M pipelined GEMM =================
// M = batch*frames = 6896 rows. Tile 128(M) x 64(N cols = 32 bins), BK=64.
// 17 active N-tiles; K-loop = 3-buffer depth-2 pipeline, counted vmcnt (T3/T4).
#define MROWS   (NBATCH * NFRAMES)      // 6896
#define BM2     128
#define BN2     64
#define BK2     64
#define MT2     54                      // ceil(6896/128)
#define NT2     17
#define TABCOLS 1088                    // 17*64 cols built
#define XPITCH  222552                  // bf16 elems per batch (NSAMP+2048 -> mult 8)
#define XPTOT   (NBATCH * XPITCH)       // 3,560,832 elems
#define NCHUNK  (XPITCH / 8)            // 27819
#define CVTBLK  ((NBATCH * NCHUNK + 255) / 256)   // 1739

// ---- fused prep: x->bf16 xp (blocks < CVTBLK) + swizzled atom table --------
__global__ void prep_all(const float* __restrict__ x,
                         __hip_bfloat16* __restrict__ xp,
                         __hip_bfloat16* __restrict__ tab) {
    const int bid = blockIdx.x;
    if (bid < CVTBLK) {
        const int idx = bid * 256 + threadIdx.x;
        if (idx >= NBATCH * NCHUNK) return;
        const int b  = idx / NCHUNK;
        const int c  = idx - b * NCHUNK;
        const int i0 = c * 8;
        const float* xb = x + (size_t)b * NSAMP;
        const int g0 = i0 - PADW;
        union { short8 v; unsigned short u[8]; } pk;
        if (g0 >= 0 && g0 + 8 <= NSAMP) {
            const float4 f0 = *(const float4*)(xb + g0);
            const float4 f1 = *(const float4*)(xb + g0 + 4);
            const float vv[8] = {f0.x, f0.y, f0.z, f0.w, f1.x, f1.y, f1.z, f1.w};
            #pragma unroll
            for (int e = 0; e < 8; ++e) {
                __hip_bfloat16 h = __float2bfloat16(vv[e]);
                pk.u[e] = *(unsigned short*)&h;
            }
        } else {
            #pragma unroll
            for (int e = 0; e < 8; ++e) {
                const int g = g0 + e;
                const float v = (g >= 0 && g < NSAMP) ? xb[g] : 0.f;
                __hip_bfloat16 h = __float2bfloat16(v);
                pk.u[e] = *(unsigned short*)&h;
            }
        }
        *(short8*)(xp + (size_t)b * XPITCH + i0) = pk.v;
        return;
    }
    // ---- atom table col, PRE-SWIZZLED: value(k) at chunk (k/8)^(col&7) -----
    const int col = bid - CVTBLK;                     // 0..1087
    const int bin = col >> 1;
    const int ri  = col & 1;
    __hip_bfloat16* row = tab + (size_t)col * NFFT;
    // zero the whole row (swizzle-invariant), then fill support
    {
        const short8 z8 = {0,0,0,0,0,0,0,0};
        *(short8*)(row + threadIdx.x * 8) = z8;
    }
    if (bin >= NBINS) return;
    __syncthreads();
    const double freq  = 27.5 * exp2((double)bin / 60.0);
    const double r     = exp2(2.0 / 60.0);
    const double alpha = (r - 1.0) / (r + 1.0);
    const double len   = (1.0 / alpha) * (double)SRATE / (freq + 30.0 / alpha);
    const int    nk    = (int)floor(len);
    const int    s     = (NFFT - nk) / 2;
    const float  ampf  = (float)((2.0 / (double)(nk - 1)) / sqrt(len));
    const float  winc  = 2.0f / (float)(nk - 1);
    const float  phsf  = (float)(2.0 * freq / (double)SRATE);  // revolutions/tap
    const int xr = col & 7;
    for (int tp = threadIdx.x; tp < nk; tp += 256) {
        const float w = 0.5f - 0.5f * cospif(winc * (float)tp);
        const float ph = fmodf(phsf * (float)tp, 2.0f);
        float sp, cp;
        sincospif(ph, &sp, &cp);
        const float val = ri ? (-w * ampf * sp) : (w * ampf * cp);
        const int t = s + tp;
        const int kpos = ((((t >> 3) ^ xr) & 0xff) << 3) | (t & 7);
        row[kpos] = __float2bfloat16(val);
    }
}

// ---- GEMM: out[row*540+bin] = |sum_k xp_row[k] * atom_col[k]| --------------
__device__ __forceinline__ short8 lds_frag(const char* base, int row, int ko) {
    const int off = (row << 7) + (((ko >> 3) ^ (row & 7)) << 4);
    return *(const short8*)(base + off);
}

__global__ __launch_bounds__(256, 2) void vqt_gemm4(const __hip_bfloat16* __restrict__ xp,
                                                    const __hip_bfloat16* __restrict__ tab,
                                                    float* __restrict__ out) {
    // 72 KB: 3 x [A 16K | B 8K] -> 2 blocks/CU
    __shared__ uint4 smem4[4608];
    const int mt = blockIdx.x, nt = blockIdx.y;
    const int row0 = mt * BM2;
    const int n0   = nt * BN2;

    // K clip from lowest (longest-support) bin of tile (supports nested)
    const int    bin0  = n0 >> 1;
    const double freq  = 27.5 * exp2((double)bin0 / 60.0);
    const double rr    = exp2(2.0 / 60.0);
    const double alpha = (rr - 1.0) / (rr + 1.0);
    const double len   = (1.0 / alpha) * (double)SRATE / (freq + 30.0 / alpha);
    const int    nk    = (int)floor(len);
    const int    s     = (NFFT - nk) / 2;
    const int    k0    = s & ~(BK2 - 1);
    int          k1    = (s + nk + BK2 - 1) & ~(BK2 - 1);
    if (k1 > NFFT) k1 = NFFT;
    const int nsteps = (k1 - k0) >> 6;                // 6..24

    const int t    = threadIdx.x;
    const int lane = t & 63;
    const int w    = t >> 6;
    const int wr   = w >> 1, wc = w & 1;              // wave -> 64x32 sub-tile
    const int l15  = lane & 15, kq = lane >> 4;

    // staging sources: thread t stages 16B chunk c = t + 256p
    const __hip_bfloat16* srcA[4];
    const __hip_bfloat16* srcB[2];
    #pragma unroll
    for (int p = 0; p < 4; ++p) {
        const int c  = t + 256 * p;
        const int lr = c >> 3;                        // A row 0..127
        const int kc = c & 7;
        int row = row0 + lr;
        if (row > MROWS - 1) row = MROWS - 1;
        const int bb = row / NFRAMES;
        const int ff = row - bb * NFRAMES;
        srcA[p] = xp + (size_t)bb * XPITCH + (size_t)ff * HOPSZ
                     + ((kc ^ (lr & 7)) << 3) + k0;
    }
    #pragma unroll
    for (int p = 0; p < 2; ++p) {
        const int c  = t + 256 * p;
        const int lr = c >> 3;                        // B row 0..63
        const int kc = c & 7;
        srcB[p] = tab + (size_t)(n0 + lr) * NFFT + (kc << 3) + k0;  // pre-swizzled
    }

    f32x4 acc[4][2] = {};

    // one STAGE = 6 gload_lds per thread (4 A + 2 B), advances K by 64
    #define STAGE(BUF)                                                            \
        do {                                                                      \
            const int cb = (BUF) * 1536;                                          \
            _Pragma("unroll")                                                     \
            for (int p = 0; p < 4; ++p) {                                         \
                __builtin_amdgcn_global_load_lds((const void*)srcA[p],            \
                    (void*)&smem4[cb + p * 256 + w * 64], 16, 0, 0);              \
                srcA[p] += BK2;                                                   \
            }                                                                     \
            _Pragma("unroll")                                                     \
            for (int p = 0; p < 2; ++p) {                                         \
                __builtin_amdgcn_global_load_lds((const void*)srcB[p],            \
                    (void*)&smem4[cb + 1024 + p * 256 + w * 64], 16, 0, 0);       \
                srcB[p] += BK2;                                                   \
            }                                                                     \
        } while (0)

    STAGE(0);
    STAGE(1);

    int cur = 0, stg = 2;
    for (int step = 0; step < nsteps; ++step) {
        // counted vmcnt: 12 outstanding at entry; retire oldest 6 (= cur's).
        if (step + 1 < nsteps) {
            asm volatile("s_waitcnt vmcnt(6)" ::: "memory");
        } else {
            asm volatile("s_waitcnt vmcnt(0)" ::: "memory");
        }
        __builtin_amdgcn_sched_barrier(0);
        __builtin_amdgcn_s_barrier();
        __builtin_amdgcn_sched_barrier(0);
        if (step + 2 < nsteps) {
            STAGE(stg);
            stg = (stg == 2) ? 0 : stg + 1;
        }
        const char* Ab = (const char*)smem4 + cur * 24576;
        const char* Bb = Ab + 16384;
        #pragma unroll
        for (int ks = 0; ks < 2; ++ks) {
            const int ko = ks * 32 + kq * 8;
            short8 af[4], bf[2];
            #pragma unroll
            for (int i = 0; i < 4; ++i) af[i] = lds_frag(Ab, wr * 64 + i * 16 + l15, ko);
            #pragma unroll
            for (int j = 0; j < 2; ++j) bf[j] = lds_frag(Bb, wc * 32 + j * 16 + l15, ko);
            #pragma unroll
            for (int i = 0; i < 4; ++i)
                #pragma unroll
                for (int j = 0; j < 2; ++j)
                    acc[i][j] = __builtin_amdgcn_mfma_f32_16x16x32_bf16(af[i], bf[j], acc[i][j], 0, 0, 0);
        }
        cur = (cur == 2) ? 0 : cur + 1;
    }
    #undef STAGE

    // ---- epilogue: |(re,im)| of adjacent-lane pairs, compacted to 16 bins
    const int rowb = row0 + wr * 64;
    const int binb = (n0 + wc * 32) >> 1;
    const int srcl = (lane & 48) | ((l15 & 7) << 1);
    #pragma unroll
    for (int i = 0; i < 4; ++i) {
        #pragma unroll
        for (int reg = 0; reg < 4; ++reg) {
            const float v0 = acc[i][0][reg];
            const float v1 = acc[i][1][reg];
            const float p0 = __shfl_xor(v0, 1);
            const float p1 = __shfl_xor(v1, 1);
            const float m0 = sqrtf(v0 * v0 + p0 * p0);
            const float m1 = sqrtf(v1 * v1 + p1 * p1);
            const float r0 = __shfl(m0, srcl);
            const float r1 = __shfl(m1, srcl);
            const float m  = (l15 < 8) ? r0 : r1;
            const int row = rowb + i * 16 + kq * 4 + reg;
            const int bin = binb + l15;
            if (row < MROWS && bin < NBINS)
                out[(size_t)row * NBINS + bin] = m;
        }
    }
}

// ======================= PATH B fallback: round-2 kernel ====================
#define NPADB   544
#define NCOLS   1088
#define BM 64
#define BN 64
#define BK 64
#define MTILES 7
#define NTILES 17
#define APITCH 72

__global__ void build_tab(__hip_bfloat16* __restrict__ tab) {
    const int bin = blockIdx.x;
    __hip_bfloat16* rowre = tab + (size_t)(2 * bin) * NFFT;
    __hip_bfloat16* rowim = rowre + NFFT;
    if (bin >= NBINS) {
        const __hip_bfloat16 z = __float2bfloat16(0.f);
        for (int t = threadIdx.x; t < NFFT; t += blockDim.x) { rowre[t] = z; rowim[t] = z; }
        return;
    }
    const double freq  = 27.5 * exp2((double)bin / 60.0);
    const double r     = exp2(2.0 / 60.0);
    const double alpha = (r - 1.0) / (r + 1.0);
    const double len   = (1.0 / alpha) * (double)SRATE / (freq + 30.0 / alpha);
    const int    nk    = (int)floor(len);
    const int    s     = (NFFT - nk) / 2;
    const double amp   = (2.0 / (double)(nk - 1)) / sqrt(len);
    for (int t = threadIdx.x; t < NFFT; t += blockDim.x) {
        float re = 0.f, im = 0.f;
        const int tp = t - s;
        if (tp >= 0 && tp < nk) {
            const double w  = 0.5 - 0.5 * cos(2.0 * PI_D * (double)tp / (double)(nk - 1));
            const double ph = fmod(2.0 * freq * (double)tp / (double)SRATE, 2.0);
            double sp, cp;
            sincospi(ph, &sp, &cp);
            re = (float)(w * amp * cp);
            im = (float)(-w * amp * sp);
        }
        rowre[t] = __float2bfloat16(re);
        rowim[t] = __float2bfloat16(im);
    }
}

__global__ __launch_bounds__(256) void vqt_gemm(const float* __restrict__ x,
                                                const __hip_bfloat16* __restrict__ tab,
                                                float* __restrict__ out) {
    __shared__ __hip_bfloat16 As[BM * APITCH];
    __shared__ __hip_bfloat16 Bs[BN * APITCH];
    const int mt = blockIdx.x, nt = blockIdx.y, b = blockIdx.z;
    const int n0 = nt * BN;
    const int    bin0  = n0 >> 1;
    const double freq  = 27.5 * exp2((double)bin0 / 60.0);
    const double r     = exp2(2.0 / 60.0);
    const double alpha = (r - 1.0) / (r + 1.0);
    const double len   = (1.0 / alpha) * (double)SRATE / (freq + 30.0 / alpha);
    const int    nk    = (int)floor(len);
    const int    s     = (NFFT - nk) / 2;
    const int    k0    = s & ~(BK - 1);
    int          k1    = (s + nk + BK - 1) & ~(BK - 1);
    if (k1 > NFFT) k1 = NFFT;
    const int tid  = threadIdx.x;
    const int lane = tid & 63;
    const int wid  = tid >> 6;
    const int wr   = wid >> 1, wc = wid & 1;
    const int sr   = tid >> 2, sq = tid & 3;
    const float* xb     = x + (size_t)b * NSAMP;
    const int    f_base = mt * BM;
    const long arow_off = (long)(f_base + sr) * HOPSZ - PADW + sq * 16;
    const __hip_bfloat16* brow = tab + (size_t)(n0 + sr) * NFFT + sq * 16;
    f32x4 acc[2][2] = {};
    for (int kt = k0; kt < k1; kt += BK) {
        union { short8 v[2]; unsigned short u[16]; } pk;
        #pragma unroll
        for (int v = 0; v < 4; ++v) {
            const long g = arow_off + kt + v * 4;
            float4 t4 = {0.f, 0.f, 0.f, 0.f};
            if (g >= 0 && g + 4 <= (long)NSAMP) t4 = *(const float4*)(xb + g);
            __hip_bfloat16 h0 = __float2bfloat16(t4.x);
            __hip_bfloat16 h1 = __float2bfloat16(t4.y);
            __hip_bfloat16 h2 = __float2bfloat16(t4.z);
            __hip_bfloat16 h3 = __float2bfloat16(t4.w);
            pk.u[4 * v + 0] = *(unsigned short*)&h0;
            pk.u[4 * v + 1] = *(unsigned short*)&h1;
            pk.u[4 * v + 2] = *(unsigned short*)&h2;
            pk.u[4 * v + 3] = *(unsigned short*)&h3;
        }
        { short8* dst = (short8*)(As + sr * APITCH + sq * 16); dst[0] = pk.v[0]; dst[1] = pk.v[1]; }
        { const short8* src = (const short8*)(brow + kt);
          short8* dst = (short8*)(Bs + sr * APITCH + sq * 16); dst[0] = src[0]; dst[1] = src[1]; }
        __syncthreads();
        #pragma unroll
        for (int ks = 0; ks < 2; ++ks) {
            const int kc = ks * 32 + (lane >> 4) * 8;
            const short8 a0 = *(const short8*)(As + (wr * 32 +      (lane & 15)) * APITCH + kc);
            const short8 a1 = *(const short8*)(As + (wr * 32 + 16 + (lane & 15)) * APITCH + kc);
            const short8 b0 = *(const short8*)(Bs + (wc * 32 +      (lane & 15)) * APITCH + kc);
            const short8 b1 = *(const short8*)(Bs + (wc * 32 + 16 + (lane & 15)) * APITCH + kc);
            acc[0][0] = __builtin_amdgcn_mfma_f32_16x16x32_bf16(a0, b0, acc[0][0], 0, 0, 0);
            acc[0][1] = __builtin_amdgcn_mfma_f32_16x16x32_bf16(a0, b1, acc[0][1], 0, 0, 0);
            acc[1][0] = __builtin_amdgcn_mfma_f32_16x16x32_bf16(a1, b0, acc[1][0], 0, 0, 0);
            acc[1][1] = __builtin_amdgcn_mfma_f32_16x16x32_bf16(a1, b1, acc[1][1], 0, 0, 0);
        }
        __syncthreads();
    }
    const int colc = lane & 15, rg = lane >> 4;
    float* outb = out + (size_t)b * NFRAMES * NBINS;
    #pragma unroll
    for (int i = 0; i < 2; ++i)
        #pragma unroll
        for (int j = 0; j < 2; ++j)
            #pragma unroll
            for (int reg = 0; reg < 4; ++reg) {
                const float v = acc[i][j][reg];
                const float p = __shfl_xor(v, 1);
                if (!(lane & 1)) {
                    const int f   = f_base + wr * 32 + i * 16 + rg * 4 + reg;
                    const int col = n0 + wc * 32 + j * 16 + colc;
                    const int bin = col >> 1;
                    if (f < NFRAMES && bin < NBINS)
                        outb[(size_t)f * NBINS + bin] = sqrtf(v * v + p * p);
                }
            }
}

extern "C" void kernel_launch(void* const* d_in, const int* in_sizes, int n_in,
                              void* d_out, int out_size, void* d_ws, size_t ws_size,
                              hipStream_t stream) {
    const float* x = (const float*)d_in[0];
    float* out = (float*)d_out;
    const size_t needA = (size_t)(XPTOT + (size_t)TABCOLS * NFFT) * 2;  // 11.58 MB
    const size_t needB = (size_t)NCOLS * NFFT * sizeof(__hip_bfloat16); // 4.46 MB
    if (ws_size >= needA) {
        __hip_bfloat16* xp  = (__hip_bfloat16*)d_ws;
        __hip_bfloat16* tab = xp + XPTOT;
        prep_all<<<dim3(CVTBLK + TABCOLS), dim3(256), 0, stream>>>(x, xp, tab);
        vqt_gemm4<<<dim3(MT2, NT2), dim3(256), 0, stream>>>(xp, tab, out);
    } else if (ws_size >= needB) {
        build_tab<<<dim3(NPADB), dim3(256), 0, stream>>>((__hip_bfloat16*)d_ws);
        vqt_gemm<<<dim3(MTILES, NTILES, NBATCH), dim3(256), 0, stream>>>(
            x, (const __hip_bfloat16*)d_ws, out);
    }
}

// Round 6
// 52.131 us; speedup vs baseline: 1.0815x; 1.0806x over previous
//
#include <hip/hip_runtime.h>
#include <hip/hip_bf16.h>
#include <math.h>

#define SRATE   44100
#define HOPSZ   512
#define NFFT    2048
#define PADW    1024
#define NBINS   540
#define NFRAMES 431
#define NSAMP   220500
#define NBATCH  16

#define PI_D 3.14159265358979323846

typedef __attribute__((ext_vector_type(8))) short short8;
typedef __attribute__((ext_vector_type(4))) float f32x4;

// ======================= PATH A: flattened-M pipelined GEMM =================
// M = batch*frames = 6896 rows. Tile 64(M) x 64(N cols = 32 bins), BK=64.
// 1836 blocks (3 resident/CU at 48KB LDS); 3-buffer counted-vmcnt pipeline.
#define MROWS   (NBATCH * NFRAMES)      // 6896
#define BM2     64
#define BN2     64
#define BK2     64
#define MT2     108                     // ceil(6896/64)
#define NT2     17
#define TABCOLS 1088                    // 17*64 cols built
#define XPITCH  222552                  // bf16 elems per batch (NSAMP+2048 -> mult 8)
#define XPTOT   (NBATCH * XPITCH)       // 3,560,832 elems
#define NCHUNK  (XPITCH / 8)            // 27819
#define CVTBLK  ((NBATCH * NCHUNK + 255) / 256)   // 1739
#define KKOFF   (XPTOT + (size_t)TABCOLS * NFFT)  // bf16-elem offset of kktab

// ---- fused prep: x->bf16 xp + swizzled atom table + K-clip table -----------
__global__ void prep_all(const float* __restrict__ x,
                         __hip_bfloat16* __restrict__ xp,
                         __hip_bfloat16* __restrict__ tab,
                         int2* __restrict__ kktab) {
    const int bid = blockIdx.x;
    if (bid < CVTBLK) {
        const int idx = bid * 256 + threadIdx.x;
        if (idx >= NBATCH * NCHUNK) return;
        const int b  = idx / NCHUNK;
        const int c  = idx - b * NCHUNK;
        const int i0 = c * 8;
        const float* xb = x + (size_t)b * NSAMP;
        const int g0 = i0 - PADW;
        union { short8 v; unsigned short u[8]; } pk;
        if (g0 >= 0 && g0 + 8 <= NSAMP) {
            const float4 f0 = *(const float4*)(xb + g0);
            const float4 f1 = *(const float4*)(xb + g0 + 4);
            const float vv[8] = {f0.x, f0.y, f0.z, f0.w, f1.x, f1.y, f1.z, f1.w};
            #pragma unroll
            for (int e = 0; e < 8; ++e) {
                __hip_bfloat16 h = __float2bfloat16(vv[e]);
                pk.u[e] = *(unsigned short*)&h;
            }
        } else {
            #pragma unroll
            for (int e = 0; e < 8; ++e) {
                const int g = g0 + e;
                const float v = (g >= 0 && g < NSAMP) ? xb[g] : 0.f;
                __hip_bfloat16 h = __float2bfloat16(v);
                pk.u[e] = *(unsigned short*)&h;
            }
        }
        *(short8*)(xp + (size_t)b * XPITCH + i0) = pk.v;
        return;
    }
    if (bid == CVTBLK + TABCOLS) {
        // K-clip table per N-tile (lowest bin = longest support; nested)
        const int nt = threadIdx.x;
        if (nt < NT2) {
            const int    bin0  = (nt * BN2) >> 1;
            const double freq  = 27.5 * exp2((double)bin0 / 60.0);
            const double r     = exp2(2.0 / 60.0);
            const double alpha = (r - 1.0) / (r + 1.0);
            const double len   = (1.0 / alpha) * (double)SRATE / (freq + 30.0 / alpha);
            const int    nk    = (int)floor(len);
            const int    s     = (NFFT - nk) / 2;
            const int    k0    = s & ~(BK2 - 1);
            int          k1    = (s + nk + BK2 - 1) & ~(BK2 - 1);
            if (k1 > NFFT) k1 = NFFT;
            kktab[nt] = make_int2(k0, (k1 - k0) >> 6);
        }
        return;
    }
    // ---- atom table col, PRE-SWIZZLED: value(k) at chunk (k/8)^(col&7) -----
    const int col = bid - CVTBLK;                     // 0..1087
    const int bin = col >> 1;
    const int ri  = col & 1;
    __hip_bfloat16* row = tab + (size_t)col * NFFT;
    {
        const short8 z8 = {0,0,0,0,0,0,0,0};
        *(short8*)(row + threadIdx.x * 8) = z8;
    }
    if (bin >= NBINS) return;
    __syncthreads();
    const double freq  = 27.5 * exp2((double)bin / 60.0);
    const double r     = exp2(2.0 / 60.0);
    const double alpha = (r - 1.0) / (r + 1.0);
    const double len   = (1.0 / alpha) * (double)SRATE / (freq + 30.0 / alpha);
    const int    nk    = (int)floor(len);
    const int    s     = (NFFT - nk) / 2;
    const float  ampf  = (float)((2.0 / (double)(nk - 1)) / sqrt(len));
    const float  winc  = 2.0f / (float)(nk - 1);
    const float  phsf  = (float)(2.0 * freq / (double)SRATE);  // revolutions/tap
    const int xr = col & 7;
    for (int tp = threadIdx.x; tp < nk; tp += 256) {
        const float w = 0.5f - 0.5f * cospif(winc * (float)tp);
        const float ph = fmodf(phsf * (float)tp, 2.0f);
        float sp, cp;
        sincospif(ph, &sp, &cp);
        const float val = ri ? (-w * ampf * sp) : (w * ampf * cp);
        const int t = s + tp;
        const int kpos = ((((t >> 3) ^ xr) & 0xff) << 3) | (t & 7);
        row[kpos] = __float2bfloat16(val);
    }
}

// ---- GEMM: out[row*540+bin] = |sum_k xp_row[k] * atom_col[k]| --------------
__device__ __forceinline__ short8 lds_frag(const char* base, int row, int ko) {
    const int off = (row << 7) + (((ko >> 3) ^ (row & 7)) << 4);
    return *(const short8*)(base + off);
}

__global__ __launch_bounds__(256, 3) void vqt_gemm5(const __hip_bfloat16* __restrict__ xp,
                                                    const __hip_bfloat16* __restrict__ tab,
                                                    const int2* __restrict__ kktab,
                                                    float* __restrict__ out) {
    // 48 KB: 3 x [A 8K | B 8K] -> 3 blocks/CU
    __shared__ uint4 smem4[3072];
    const int mt = blockIdx.x, nt = blockIdx.y;
    const int row0 = mt * BM2;
    const int n0   = nt * BN2;

    const int2 kkv   = kktab[nt];
    const int  k0    = kkv.x;
    const int  nsteps = kkv.y;                        // 6..24

    const int t    = threadIdx.x;
    const int lane = t & 63;
    const int w    = t >> 6;
    const int wr   = w >> 1, wc = w & 1;              // wave -> 32x32 sub-tile
    const int l15  = lane & 15, kq = lane >> 4;

    // staging sources: thread t stages 16B chunk c = t + 256p (A and B: 2 each)
    const __hip_bfloat16* srcA[2];
    const __hip_bfloat16* srcB[2];
    #pragma unroll
    for (int p = 0; p < 2; ++p) {
        const int c  = t + 256 * p;
        const int lr = c >> 3;                        // row 0..63
        const int kc = c & 7;
        int row = row0 + lr;
        if (row > MROWS - 1) row = MROWS - 1;
        const int bb = row / NFRAMES;
        const int ff = row - bb * NFRAMES;
        srcA[p] = xp + (size_t)bb * XPITCH + (size_t)ff * HOPSZ
                     + ((kc ^ (lr & 7)) << 3) + k0;
        srcB[p] = tab + (size_t)(n0 + lr) * NFFT + (kc << 3) + k0;  // pre-swizzled
    }

    f32x4 acc[2][2] = {};

    // one STAGE = 4 gload_lds per thread (2 A + 2 B), advances K by 64
    #define STAGE(BUF)                                                            \
        do {                                                                      \
            const int cb = (BUF) * 1024;                                          \
            _Pragma("unroll")                                                     \
            for (int p = 0; p < 2; ++p) {                                         \
                __builtin_amdgcn_global_load_lds((const void*)srcA[p],            \
                    (void*)&smem4[cb + p * 256 + w * 64], 16, 0, 0);              \
                srcA[p] += BK2;                                                   \
            }                                                                     \
            _Pragma("unroll")                                                     \
            for (int p = 0; p < 2; ++p) {                                         \
                __builtin_amdgcn_global_load_lds((const void*)srcB[p],            \
                    (void*)&smem4[cb + 512 + p * 256 + w * 64], 16, 0, 0);        \
                srcB[p] += BK2;                                                   \
            }                                                                     \
        } while (0)

    STAGE(0);
    STAGE(1);

    int cur = 0, stg = 2;
    for (int step = 0; step < nsteps; ++step) {
        // counted vmcnt: 8 outstanding at entry; retire oldest 4 (= cur's).
        if (step + 1 < nsteps) {
            asm volatile("s_waitcnt vmcnt(4)" ::: "memory");
        } else {
            asm volatile("s_waitcnt vmcnt(0)" ::: "memory");
        }
        __builtin_amdgcn_sched_barrier(0);
        __builtin_amdgcn_s_barrier();
        __builtin_amdgcn_sched_barrier(0);
        if (step + 2 < nsteps) {
            STAGE(stg);
            stg = (stg == 2) ? 0 : stg + 1;
        }
        const char* Ab = (const char*)smem4 + cur * 16384;
        const char* Bb = Ab + 8192;
        #pragma unroll
        for (int ks = 0; ks < 2; ++ks) {
            const int ko = ks * 32 + kq * 8;
            short8 af[2], bf[2];
            #pragma unroll
            for (int i = 0; i < 2; ++i) af[i] = lds_frag(Ab, wr * 32 + i * 16 + l15, ko);
            #pragma unroll
            for (int j = 0; j < 2; ++j) bf[j] = lds_frag(Bb, wc * 32 + j * 16 + l15, ko);
            #pragma unroll
            for (int i = 0; i < 2; ++i)
                #pragma unroll
                for (int j = 0; j < 2; ++j)
                    acc[i][j] = __builtin_amdgcn_mfma_f32_16x16x32_bf16(af[i], bf[j], acc[i][j], 0, 0, 0);
        }
        cur = (cur == 2) ? 0 : cur + 1;
    }
    #undef STAGE

    // ---- epilogue: |(re,im)| of adjacent-lane pairs, compacted to 16 bins
    const int rowb = row0 + wr * 32;
    const int binb = (n0 + wc * 32) >> 1;
    const int srcl = (lane & 48) | ((l15 & 7) << 1);
    #pragma unroll
    for (int i = 0; i < 2; ++i) {
        #pragma unroll
        for (int reg = 0; reg < 4; ++reg) {
            const float v0 = acc[i][0][reg];
            const float v1 = acc[i][1][reg];
            const float p0 = __shfl_xor(v0, 1);
            const float p1 = __shfl_xor(v1, 1);
            const float m0 = sqrtf(v0 * v0 + p0 * p0);
            const float m1 = sqrtf(v1 * v1 + p1 * p1);
            const float r0 = __shfl(m0, srcl);
            const float r1 = __shfl(m1, srcl);
            const float m  = (l15 < 8) ? r0 : r1;
            const int row = rowb + i * 16 + kq * 4 + reg;
            const int bin = binb + l15;
            if (row < MROWS && bin < NBINS)
                out[(size_t)row * NBINS + bin] = m;
        }
    }
}

// ======================= PATH B fallback: round-2 kernel ====================
#define NPADB   544
#define NCOLS   1088
#define BM 64
#define BN 64
#define BK 64
#define MTILES 7
#define NTILES 17
#define APITCH 72

__global__ void build_tab(__hip_bfloat16* __restrict__ tab) {
    const int bin = blockIdx.x;
    __hip_bfloat16* rowre = tab + (size_t)(2 * bin) * NFFT;
    __hip_bfloat16* rowim = rowre + NFFT;
    if (bin >= NBINS) {
        const __hip_bfloat16 z = __float2bfloat16(0.f);
        for (int t = threadIdx.x; t < NFFT; t += blockDim.x) { rowre[t] = z; rowim[t] = z; }
        return;
    }
    const double freq  = 27.5 * exp2((double)bin / 60.0);
    const double r     = exp2(2.0 / 60.0);
    const double alpha = (r - 1.0) / (r + 1.0);
    const double len   = (1.0 / alpha) * (double)SRATE / (freq + 30.0 / alpha);
    const int    nk    = (int)floor(len);
    const int    s     = (NFFT - nk) / 2;
    const double amp   = (2.0 / (double)(nk - 1)) / sqrt(len);
    for (int t = threadIdx.x; t < NFFT; t += blockDim.x) {
        float re = 0.f, im = 0.f;
        const int tp = t - s;
        if (tp >= 0 && tp < nk) {
            const double w  = 0.5 - 0.5 * cos(2.0 * PI_D * (double)tp / (double)(nk - 1));
            const double ph = fmod(2.0 * freq * (double)tp / (double)SRATE, 2.0);
            double sp, cp;
            sincospi(ph, &sp, &cp);
            re = (float)(w * amp * cp);
            im = (float)(-w * amp * sp);
        }
        rowre[t] = __float2bfloat16(re);
        rowim[t] = __float2bfloat16(im);
    }
}

__global__ __launch_bounds__(256) void vqt_gemm(const float* __restrict__ x,
                                                const __hip_bfloat16* __restrict__ tab,
                                                float* __restrict__ out) {
    __shared__ __hip_bfloat16 As[BM * APITCH];
    __shared__ __hip_bfloat16 Bs[BN * APITCH];
    const int mt = blockIdx.x, nt = blockIdx.y, b = blockIdx.z;
    const int n0 = nt * BN;
    const int    bin0  = n0 >> 1;
    const double freq  = 27.5 * exp2((double)bin0 / 60.0);
    const double r     = exp2(2.0 / 60.0);
    const double alpha = (r - 1.0) / (r + 1.0);
    const double len   = (1.0 / alpha) * (double)SRATE / (freq + 30.0 / alpha);
    const int    nk    = (int)floor(len);
    const int    s     = (NFFT - nk) / 2;
    const int    k0    = s & ~(BK - 1);
    int          k1    = (s + nk + BK - 1) & ~(BK - 1);
    if (k1 > NFFT) k1 = NFFT;
    const int tid  = threadIdx.x;
    const int lane = tid & 63;
    const int wid  = tid >> 6;
    const int wr   = wid >> 1, wc = wid & 1;
    const int sr   = tid >> 2, sq = tid & 3;
    const float* xb     = x + (size_t)b * NSAMP;
    const int    f_base = mt * BM;
    const long arow_off = (long)(f_base + sr) * HOPSZ - PADW + sq * 16;
    const __hip_bfloat16* brow = tab + (size_t)(n0 + sr) * NFFT + sq * 16;
    f32x4 acc[2][2] = {};
    for (int kt = k0; kt < k1; kt += BK) {
        union { short8 v[2]; unsigned short u[16]; } pk;
        #pragma unroll
        for (int v = 0; v < 4; ++v) {
            const long g = arow_off + kt + v * 4;
            float4 t4 = {0.f, 0.f, 0.f, 0.f};
            if (g >= 0 && g + 4 <= (long)NSAMP) t4 = *(const float4*)(xb + g);
            __hip_bfloat16 h0 = __float2bfloat16(t4.x);
            __hip_bfloat16 h1 = __float2bfloat16(t4.y);
            __hip_bfloat16 h2 = __float2bfloat16(t4.z);
            __hip_bfloat16 h3 = __float2bfloat16(t4.w);
            pk.u[4 * v + 0] = *(unsigned short*)&h0;
            pk.u[4 * v + 1] = *(unsigned short*)&h1;
            pk.u[4 * v + 2] = *(unsigned short*)&h2;
            pk.u[4 * v + 3] = *(unsigned short*)&h3;
        }
        { short8* dst = (short8*)(As + sr * APITCH + sq * 16); dst[0] = pk.v[0]; dst[1] = pk.v[1]; }
        { const short8* src = (const short8*)(brow + kt);
          short8* dst = (short8*)(Bs + sr * APITCH + sq * 16); dst[0] = src[0]; dst[1] = src[1]; }
        __syncthreads();
        #pragma unroll
        for (int ks = 0; ks < 2; ++ks) {
            const int kc = ks * 32 + (lane >> 4) * 8;
            const short8 a0 = *(const short8*)(As + (wr * 32 +      (lane & 15)) * APITCH + kc);
            const short8 a1 = *(const short8*)(As + (wr * 32 + 16 + (lane & 15)) * APITCH + kc);
            const short8 b0 = *(const short8*)(Bs + (wc * 32 +      (lane & 15)) * APITCH + kc);
            const short8 b1 = *(const short8*)(Bs + (wc * 32 + 16 + (lane & 15)) * APITCH + kc);
            acc[0][0] = __builtin_amdgcn_mfma_f32_16x16x32_bf16(a0, b0, acc[0][0], 0, 0, 0);
            acc[0][1] = __builtin_amdgcn_mfma_f32_16x16x32_bf16(a0, b1, acc[0][1], 0, 0, 0);
            acc[1][0] = __builtin_amdgcn_mfma_f32_16x16x32_bf16(a1, b0, acc[1][0], 0, 0, 0);
            acc[1][1] = __builtin_amdgcn_mfma_f32_16x16x32_bf16(a1, b1, acc[1][1], 0, 0, 0);
        }
        __syncthreads();
    }
    const int colc = lane & 15, rg = lane >> 4;
    float* outb = out + (size_t)b * NFRAMES * NBINS;
    #pragma unroll
    for (int i = 0; i < 2; ++i)
        #pragma unroll
        for (int j = 0; j < 2; ++j)
            #pragma unroll
            for (int reg = 0; reg < 4; ++reg) {
                const float v = acc[i][j][reg];
                const float p = __shfl_xor(v, 1);
                if (!(lane & 1)) {
                    const int f   = f_base + wr * 32 + i * 16 + rg * 4 + reg;
                    const int col = n0 + wc * 32 + j * 16 + colc;
                    const int bin = col >> 1;
                    if (f < NFRAMES && bin < NBINS)
                        outb[(size_t)f * NBINS + bin] = sqrtf(v * v + p * p);
                }
            }
}

extern "C" void kernel_launch(void* const* d_in, const int* in_sizes, int n_in,
                              void* d_out, int out_size, void* d_ws, size_t ws_size,
                              hipStream_t stream) {
    const float* x = (const float*)d_in[0];
    float* out = (float*)d_out;
    const size_t needA = KKOFF * 2 + NT2 * sizeof(int2);                // ~11.58 MB
    const size_t needB = (size_t)NCOLS * NFFT * sizeof(__hip_bfloat16); // 4.46 MB
    if (ws_size >= needA) {
        __hip_bfloat16* xp  = (__hip_bfloat16*)d_ws;
        __hip_bfloat16* tab = xp + XPTOT;
        int2* kktab = (int2*)((char*)d_ws + KKOFF * 2);
        prep_all<<<dim3(CVTBLK + TABCOLS + 1), dim3(256), 0, stream>>>(x, xp, tab, kktab);
        vqt_gemm5<<<dim3(MT2, NT2), dim3(256), 0, stream>>>(xp, tab, kktab, out);
    } else if (ws_size >= needB) {
        build_tab<<<dim3(NPADB), dim3(256), 0, stream>>>((__hip_bfloat16*)d_ws);
        vqt_gemm<<<dim3(MTILES, NTILES, NBATCH), dim3(256), 0, stream>>>(
            x, (const __hip_bfloat16*)d_ws, out);
    }
}